// Round 1
// baseline (185.236 us; speedup 1.0000x reference)
//
#include <hip/hip_runtime.h>
#include <math.h>
#include <float.h>

#define N_NODES 100000
#define N_EDGES 1200000
#define FEAT 64
#define AVG_D_LOG 2.5649493574615367f  /* log(13.0) */
#define EPS_STD 1e-5f
#define EPS_BN 1e-5
#define RED_BLOCKS 512

// ---------------------------------------------------------------- rowptr ----
// dst is sorted; rowptr[n] = first edge index with dst >= n, rowptr[N] = E.
__global__ void build_rowptr(const int* __restrict__ dst, int* __restrict__ rowptr) {
    int n = blockIdx.x * blockDim.x + threadIdx.x;
    if (n > N_NODES) return;
    int lo = 0, hi = N_EDGES;
    while (lo < hi) {
        int mid = (lo + hi) >> 1;
        if (dst[mid] < n) lo = mid + 1; else hi = mid;
    }
    rowptr[n] = lo;
}

// ------------------------------------------------------- aggregation --------
// One wave (64 lanes) per node; lane == feature. No cross-lane comms needed.
__global__ void __launch_bounds__(256) pna_agg(
    const float* __restrict__ h, const float* __restrict__ norm,
    const int* __restrict__ src, const int* __restrict__ rowptr,
    float* __restrict__ out1)
{
    const int wid  = threadIdx.x >> 6;
    const int lane = threadIdx.x & 63;
    const int node = blockIdx.x * 4 + wid;
    if (node >= N_NODES) return;

    const int start = rowptr[node];
    const int end   = rowptr[node + 1];
    const int deg   = end - start;

    const float nrm = norm[node];
    const float hn  = h[(size_t)node * FEAT + lane] * nrm;

    float pre;
    if (deg > 0) {
        float s1 = 0.f, s2 = 0.f, mx = -FLT_MAX, mn = FLT_MAX;
        for (int e = start; e < end; ++e) {
            int s = src[e];                      // wave-uniform
            float v = h[(size_t)s * FEAT + lane] * norm[s];
            s1 += v;
            s2 += v * v;
            mx = fmaxf(mx, v);
            mn = fminf(mn, v);
        }
        float invd = 1.0f / (float)deg;
        float mean = s1 * invd;
        float var  = fmaxf(s2 * invd - mean * mean, 0.0f);   // relu(...)
        float stdv = sqrtf(var + EPS_STD);
        float logD = logf((float)deg + 1.0f);
        // (1 + amp + att) scaler, times dst-node norm, /13 for the channel mean
        float factor = nrm * (1.0f + logD * (1.0f / AVG_D_LOG) + AVG_D_LOG / logD)
                           * (1.0f / 13.0f);
        pre = hn * (1.0f / 13.0f) + (mean + mx + mn + stdv) * factor;
    } else {
        pre = hn * (1.0f / 13.0f);               // zero-degree: only hn channel
    }
    out1[(size_t)node * FEAT + lane] = fmaxf(pre, 0.0f);     // ReLU
}

// -------------------------------------------------- BN stats (2-stage) ------
__global__ void __launch_bounds__(256) bn_partial(
    const float* __restrict__ out1,
    double* __restrict__ psum, double* __restrict__ psumsq)
{
    const int tid = threadIdx.x;
    const int f   = tid & 63;
    const int grp = tid >> 6;                    // 0..3
    double s = 0.0, s2 = 0.0;
    for (int n = blockIdx.x * 4 + grp; n < N_NODES; n += RED_BLOCKS * 4) {
        float v = out1[(size_t)n * FEAT + f];
        s  += (double)v;
        s2 += (double)v * (double)v;
    }
    __shared__ double ls[256], ls2[256];
    ls[tid] = s; ls2[tid] = s2;
    __syncthreads();
    if (tid < 64) {
        psum  [blockIdx.x * 64 + tid] = ls [tid] + ls [tid + 64] + ls [tid + 128] + ls [tid + 192];
        psumsq[blockIdx.x * 64 + tid] = ls2[tid] + ls2[tid + 64] + ls2[tid + 128] + ls2[tid + 192];
    }
}

__global__ void bn_finalize(const double* __restrict__ psum,
                            const double* __restrict__ psumsq,
                            const float* __restrict__ w, const float* __restrict__ b,
                            float* __restrict__ scale, float* __restrict__ shift)
{
    int f = threadIdx.x;                         // 64 threads
    double s = 0.0, s2 = 0.0;
    for (int blk = 0; blk < RED_BLOCKS; ++blk) {
        s  += psum  [blk * 64 + f];
        s2 += psumsq[blk * 64 + f];
    }
    double mu   = s / (double)N_NODES;
    double var  = s2 / (double)N_NODES - mu * mu;   // biased (training-mode) var
    double rstd = 1.0 / sqrt(var + EPS_BN);
    float sc = (float)rstd * w[f];
    scale[f] = sc;
    shift[f] = b[f] - (float)mu * sc;
}

// ------------------------------------------------------- BN apply -----------
__global__ void __launch_bounds__(256) bn_apply(
    float* __restrict__ out,
    const float* __restrict__ scale, const float* __restrict__ shift)
{
    const size_t i4 = ((size_t)blockIdx.x * blockDim.x + threadIdx.x) * 4;
    if (i4 >= (size_t)N_NODES * FEAT) return;
    float4 v = *reinterpret_cast<const float4*>(out + i4);
    const int f = (int)(i4 & 63);
    v.x = v.x * scale[f + 0] + shift[f + 0];
    v.y = v.y * scale[f + 1] + shift[f + 1];
    v.z = v.z * scale[f + 2] + shift[f + 2];
    v.w = v.w * scale[f + 3] + shift[f + 3];
    *reinterpret_cast<float4*>(out + i4) = v;
}

// ---------------------------------------------------------------------------
extern "C" void kernel_launch(void* const* d_in, const int* in_sizes, int n_in,
                              void* d_out, int out_size, void* d_ws, size_t ws_size,
                              hipStream_t stream) {
    const float* h    = (const float*)d_in[0];
    const float* norm = (const float*)d_in[1];
    /* d_in[2] = e, unused */
    const float* bnw  = (const float*)d_in[3];
    const float* bnb  = (const float*)d_in[4];
    const int*   src  = (const int*)d_in[5];
    const int*   dst  = (const int*)d_in[6];
    float* out = (float*)d_out;

    char* ws = (char*)d_ws;
    size_t off = 0;
    int* rowptr = (int*)(ws + off);
    off = ((size_t)(N_NODES + 1) * sizeof(int) + 255) & ~(size_t)255;
    double* psum   = (double*)(ws + off); off += (size_t)RED_BLOCKS * 64 * sizeof(double);
    double* psumsq = (double*)(ws + off); off += (size_t)RED_BLOCKS * 64 * sizeof(double);
    float* scale   = (float*)(ws + off);  off += 64 * sizeof(float);
    float* shift   = (float*)(ws + off);

    build_rowptr<<<(N_NODES + 1 + 255) / 256, 256, 0, stream>>>(dst, rowptr);
    pna_agg<<<(N_NODES + 3) / 4, 256, 0, stream>>>(h, norm, src, rowptr, out);
    bn_partial<<<RED_BLOCKS, 256, 0, stream>>>(out, psum, psumsq);
    bn_finalize<<<1, 64, 0, stream>>>(psum, psumsq, bnw, bnb, scale, shift);
    bn_apply<<<((N_NODES * FEAT / 4) + 255) / 256, 256, 0, stream>>>(out, scale, shift);
}

// Round 2
// 122.051 us; speedup vs baseline: 1.5177x; 1.5177x over previous
//
#include <hip/hip_runtime.h>
#include <math.h>
#include <float.h>

#define N_NODES 100000
#define N_EDGES 1200000
#define FEAT 64
#define AVG_D_LOG 2.5649493574615367f  /* log(13.0) */
#define EPS_STD 1e-5f
#define EPS_BN 1e-5
#define RED_BLOCKS 512

// ---------------------------------------------------------------- rowptr ----
// dst is sorted; rowptr[n] = first edge index with dst >= n, rowptr[N] = E.
__global__ void build_rowptr(const int* __restrict__ dst, int* __restrict__ rowptr) {
    int n = blockIdx.x * blockDim.x + threadIdx.x;
    if (n > N_NODES) return;
    int lo = 0, hi = N_EDGES;
    while (lo < hi) {
        int mid = (lo + hi) >> 1;
        if (dst[mid] < n) lo = mid + 1; else hi = mid;
    }
    rowptr[n] = lo;
}

// ---------------------------------------------------------- hn = h*norm -----
__global__ void __launch_bounds__(256) compute_hn(
    const float* __restrict__ h, const float* __restrict__ norm,
    float* __restrict__ hn)
{
    size_t i4 = ((size_t)blockIdx.x * 256 + threadIdx.x) * 4;
    if (i4 >= (size_t)N_NODES * FEAT) return;
    const int node = (int)(i4 >> 6);
    const float nr = norm[node];
    float4 v = *reinterpret_cast<const float4*>(h + i4);
    v.x *= nr; v.y *= nr; v.z *= nr; v.w *= nr;
    *reinterpret_cast<float4*>(hn + i4) = v;
}

// ------------------------------------------------------- aggregation --------
// One wave (64 lanes) per node; lane == feature. 4x unrolled gather for MLP.
__global__ void __launch_bounds__(256) pna_agg_fast(
    const float* __restrict__ hn, const float* __restrict__ norm,
    const int* __restrict__ src, const int* __restrict__ rowptr,
    float* __restrict__ out1)
{
    const int wid  = threadIdx.x >> 6;
    const int lane = threadIdx.x & 63;
    const int node = blockIdx.x * 4 + wid;
    if (node >= N_NODES) return;

    const int start = rowptr[node];
    const int end   = rowptr[node + 1];
    const int deg   = end - start;

    const float hnv = hn[(size_t)node * FEAT + lane];

    float pre;
    if (deg > 0) {
        float s1a = 0.f, s1b = 0.f, s1c = 0.f, s1d = 0.f;
        float s2a = 0.f, s2b = 0.f, s2c = 0.f, s2d = 0.f;
        float mx = -FLT_MAX, mn = FLT_MAX;
        int e = start;
        for (; e + 4 <= end; e += 4) {
            const int i0 = src[e + 0];
            const int i1 = src[e + 1];
            const int i2 = src[e + 2];
            const int i3 = src[e + 3];
            const float v0 = hn[(size_t)i0 * FEAT + lane];
            const float v1 = hn[(size_t)i1 * FEAT + lane];
            const float v2 = hn[(size_t)i2 * FEAT + lane];
            const float v3 = hn[(size_t)i3 * FEAT + lane];
            s1a += v0; s2a += v0 * v0; mx = fmaxf(mx, v0); mn = fminf(mn, v0);
            s1b += v1; s2b += v1 * v1; mx = fmaxf(mx, v1); mn = fminf(mn, v1);
            s1c += v2; s2c += v2 * v2; mx = fmaxf(mx, v2); mn = fminf(mn, v2);
            s1d += v3; s2d += v3 * v3; mx = fmaxf(mx, v3); mn = fminf(mn, v3);
        }
        for (; e < end; ++e) {
            const int s = src[e];
            const float v = hn[(size_t)s * FEAT + lane];
            s1a += v; s2a += v * v; mx = fmaxf(mx, v); mn = fminf(mn, v);
        }
        const float s1 = (s1a + s1b) + (s1c + s1d);
        const float s2 = (s2a + s2b) + (s2c + s2d);

        const float invd = 1.0f / (float)deg;
        const float mean = s1 * invd;
        const float var  = fmaxf(s2 * invd - mean * mean, 0.0f);   // relu(...)
        const float stdv = sqrtf(var + EPS_STD);
        const float logD = logf((float)deg + 1.0f);
        const float nrm  = norm[node];
        const float factor = nrm * (1.0f + logD * (1.0f / AVG_D_LOG) + AVG_D_LOG / logD)
                                 * (1.0f / 13.0f);
        pre = hnv * (1.0f / 13.0f) + (mean + mx + mn + stdv) * factor;
    } else {
        pre = hnv * (1.0f / 13.0f);              // zero-degree: only hn channel
    }
    out1[(size_t)node * FEAT + lane] = fmaxf(pre, 0.0f);     // ReLU
}

// Fallback (ws too small for hn buffer): original fused version.
__global__ void __launch_bounds__(256) pna_agg_slow(
    const float* __restrict__ h, const float* __restrict__ norm,
    const int* __restrict__ src, const int* __restrict__ rowptr,
    float* __restrict__ out1)
{
    const int wid  = threadIdx.x >> 6;
    const int lane = threadIdx.x & 63;
    const int node = blockIdx.x * 4 + wid;
    if (node >= N_NODES) return;

    const int start = rowptr[node];
    const int end   = rowptr[node + 1];
    const int deg   = end - start;

    const float nrm = norm[node];
    const float hnv = h[(size_t)node * FEAT + lane] * nrm;

    float pre;
    if (deg > 0) {
        float s1 = 0.f, s2 = 0.f, mx = -FLT_MAX, mn = FLT_MAX;
        for (int e = start; e < end; ++e) {
            int s = src[e];
            float v = h[(size_t)s * FEAT + lane] * norm[s];
            s1 += v; s2 += v * v; mx = fmaxf(mx, v); mn = fminf(mn, v);
        }
        float invd = 1.0f / (float)deg;
        float mean = s1 * invd;
        float var  = fmaxf(s2 * invd - mean * mean, 0.0f);
        float stdv = sqrtf(var + EPS_STD);
        float logD = logf((float)deg + 1.0f);
        float factor = nrm * (1.0f + logD * (1.0f / AVG_D_LOG) + AVG_D_LOG / logD)
                           * (1.0f / 13.0f);
        pre = hnv * (1.0f / 13.0f) + (mean + mx + mn + stdv) * factor;
    } else {
        pre = hnv * (1.0f / 13.0f);
    }
    out1[(size_t)node * FEAT + lane] = fmaxf(pre, 0.0f);
}

// -------------------------------------------------- BN stats (2-stage) ------
__global__ void __launch_bounds__(256) bn_partial(
    const float* __restrict__ out1,
    double* __restrict__ psum, double* __restrict__ psumsq)
{
    const int tid = threadIdx.x;
    const int fb  = tid & 15;                    // feature block of 4
    const int grp = tid >> 4;                    // 0..15 node groups
    double s0 = 0, s1 = 0, s2 = 0, s3 = 0;
    double q0 = 0, q1 = 0, q2 = 0, q3 = 0;
    for (int n = blockIdx.x * 16 + grp; n < N_NODES; n += RED_BLOCKS * 16) {
        float4 v = *reinterpret_cast<const float4*>(out1 + (size_t)n * FEAT + fb * 4);
        s0 += (double)v.x; q0 += (double)v.x * (double)v.x;
        s1 += (double)v.y; q1 += (double)v.y * (double)v.y;
        s2 += (double)v.z; q2 += (double)v.z * (double)v.z;
        s3 += (double)v.w; q3 += (double)v.w * (double)v.w;
    }
    __shared__ double ls[256 * 4];
    __shared__ double lq[256 * 4];
    ls[tid * 4 + 0] = s0; ls[tid * 4 + 1] = s1; ls[tid * 4 + 2] = s2; ls[tid * 4 + 3] = s3;
    lq[tid * 4 + 0] = q0; lq[tid * 4 + 1] = q1; lq[tid * 4 + 2] = q2; lq[tid * 4 + 3] = q3;
    __syncthreads();
    if (tid < 64) {
        const int f = tid, fblk = f >> 2, j = f & 3;
        double S = 0, Q = 0;
        for (int g = 0; g < 16; ++g) {
            S += ls[(g * 16 + fblk) * 4 + j];
            Q += lq[(g * 16 + fblk) * 4 + j];
        }
        psum  [blockIdx.x * 64 + f] = S;
        psumsq[blockIdx.x * 64 + f] = Q;
    }
}

__global__ void bn_finalize(const double* __restrict__ psum,
                            const double* __restrict__ psumsq,
                            const float* __restrict__ w, const float* __restrict__ b,
                            float* __restrict__ scale, float* __restrict__ shift)
{
    int f = threadIdx.x;                         // 64 threads
    double s = 0.0, s2 = 0.0;
    for (int blk = 0; blk < RED_BLOCKS; ++blk) {
        s  += psum  [blk * 64 + f];
        s2 += psumsq[blk * 64 + f];
    }
    double mu   = s / (double)N_NODES;
    double var  = s2 / (double)N_NODES - mu * mu;   // biased (training-mode) var
    double rstd = 1.0 / sqrt(var + EPS_BN);
    float sc = (float)rstd * w[f];
    scale[f] = sc;
    shift[f] = b[f] - (float)mu * sc;
}

// ------------------------------------------------------- BN apply -----------
__global__ void __launch_bounds__(256) bn_apply(
    float* __restrict__ out,
    const float* __restrict__ scale, const float* __restrict__ shift)
{
    const size_t i4 = ((size_t)blockIdx.x * blockDim.x + threadIdx.x) * 4;
    if (i4 >= (size_t)N_NODES * FEAT) return;
    float4 v = *reinterpret_cast<const float4*>(out + i4);
    const int f = (int)(i4 & 63);
    v.x = v.x * scale[f + 0] + shift[f + 0];
    v.y = v.y * scale[f + 1] + shift[f + 1];
    v.z = v.z * scale[f + 2] + shift[f + 2];
    v.w = v.w * scale[f + 3] + shift[f + 3];
    *reinterpret_cast<float4*>(out + i4) = v;
}

// ---------------------------------------------------------------------------
extern "C" void kernel_launch(void* const* d_in, const int* in_sizes, int n_in,
                              void* d_out, int out_size, void* d_ws, size_t ws_size,
                              hipStream_t stream) {
    const float* h    = (const float*)d_in[0];
    const float* norm = (const float*)d_in[1];
    /* d_in[2] = e, unused */
    const float* bnw  = (const float*)d_in[3];
    const float* bnb  = (const float*)d_in[4];
    const int*   src  = (const int*)d_in[5];
    const int*   dst  = (const int*)d_in[6];
    float* out = (float*)d_out;

    const size_t hn_bytes = (size_t)N_NODES * FEAT * sizeof(float);   // 25.6 MB
    char* ws = (char*)d_ws;
    size_t off = 0;
    float* hnbuf = (float*)(ws + off);
    size_t off_small = 0;                                 // layout if no hn buffer
    // full layout: [hn][rowptr][psum][psumsq][scale][shift]
    size_t o = hn_bytes;
    int* rowptr_f = (int*)(ws + o);   o += ((size_t)(N_NODES + 1) * sizeof(int) + 255) & ~(size_t)255;
    double* psum_f   = (double*)(ws + o); o += (size_t)RED_BLOCKS * 64 * sizeof(double);
    double* psumsq_f = (double*)(ws + o); o += (size_t)RED_BLOCKS * 64 * sizeof(double);
    float* scale_f   = (float*)(ws + o);  o += 256;
    float* shift_f   = (float*)(ws + o);  o += 256;
    const size_t need_full = o;

    // small layout (fallback): [rowptr][psum][psumsq][scale][shift]
    int* rowptr_s = (int*)(ws + off_small);
    off_small = ((size_t)(N_NODES + 1) * sizeof(int) + 255) & ~(size_t)255;
    double* psum_s   = (double*)(ws + off_small); off_small += (size_t)RED_BLOCKS * 64 * sizeof(double);
    double* psumsq_s = (double*)(ws + off_small); off_small += (size_t)RED_BLOCKS * 64 * sizeof(double);
    float* scale_s   = (float*)(ws + off_small);  off_small += 256;
    float* shift_s   = (float*)(ws + off_small);

    const bool fast = (ws_size >= need_full);
    int* rowptr     = fast ? rowptr_f : rowptr_s;
    double* psum    = fast ? psum_f   : psum_s;
    double* psumsq  = fast ? psumsq_f : psumsq_s;
    float* scale    = fast ? scale_f  : scale_s;
    float* shift    = fast ? shift_f  : shift_s;

    build_rowptr<<<(N_NODES + 1 + 255) / 256, 256, 0, stream>>>(dst, rowptr);
    if (fast) {
        compute_hn<<<(N_NODES * FEAT / 4 + 255) / 256, 256, 0, stream>>>(h, norm, hnbuf);
        pna_agg_fast<<<(N_NODES + 3) / 4, 256, 0, stream>>>(hnbuf, norm, src, rowptr, out);
    } else {
        pna_agg_slow<<<(N_NODES + 3) / 4, 256, 0, stream>>>(h, norm, src, rowptr, out);
    }
    bn_partial<<<RED_BLOCKS, 256, 0, stream>>>(out, psum, psumsq);
    bn_finalize<<<1, 64, 0, stream>>>(psum, psumsq, bnw, bnb, scale, shift);
    bn_apply<<<((N_NODES * FEAT / 4) + 255) / 256, 256, 0, stream>>>(out, scale, shift);
}

// Round 3
// 99.445 us; speedup vs baseline: 1.8627x; 1.2273x over previous
//
#include <hip/hip_runtime.h>
#include <hip/hip_fp16.h>
#include <math.h>
#include <float.h>

#define N_NODES 100000
#define N_EDGES 1200000
#define FEAT 64
#define AVG_D_LOG 2.5649493574615367f  /* log(13.0) */
#define EPS_STD 1e-5f
#define EPS_BN 1e-5
#define RED_BLOCKS 512
#define HN_BLOCKS 6250                 /* N_NODES*FEAT/4/256 */
#define RP_BLOCKS 391                  /* ceil((N_NODES+1)/256) */

// ----------------------------------------------- fused hn(fp16) + rowptr ----
// Blocks [0, HN_BLOCKS): hn_h[i] = (half)(h[i] * norm[i/64]), 4 elems/thread.
// Blocks [HN_BLOCKS, HN_BLOCKS+RP_BLOCKS): rowptr via binary search on dst.
__global__ void __launch_bounds__(256) hn_rowptr(
    const float* __restrict__ h, const float* __restrict__ norm,
    const int* __restrict__ dst,
    __half* __restrict__ hn_h, int* __restrict__ rowptr)
{
    const int b = blockIdx.x;
    if (b < HN_BLOCKS) {
        const size_t i4 = ((size_t)b * 256 + threadIdx.x) * 4;
        const int node = (int)(i4 >> 6);
        const float nr = norm[node];
        float4 v = *reinterpret_cast<const float4*>(h + i4);
        __half2 p0 = __floats2half2_rn(v.x * nr, v.y * nr);
        __half2 p1 = __floats2half2_rn(v.z * nr, v.w * nr);
        __half2* o = reinterpret_cast<__half2*>(hn_h + i4);
        o[0] = p0; o[1] = p1;
    } else {
        const int n = (b - HN_BLOCKS) * 256 + threadIdx.x;
        if (n > N_NODES) return;
        int lo = 0, hi = N_EDGES;
        while (lo < hi) {
            int mid = (lo + hi) >> 1;
            if (dst[mid] < n) lo = mid + 1; else hi = mid;
        }
        rowptr[n] = lo;
    }
}

// ------------------------------------------------------- aggregation --------
// One wave per node; lane == feature. fp16 gather table, 8x unrolled for MLP.
__global__ void __launch_bounds__(256) pna_agg_fast(
    const __half* __restrict__ hn, const float* __restrict__ h,
    const float* __restrict__ norm,
    const int* __restrict__ src, const int* __restrict__ rowptr,
    float* __restrict__ out1)
{
    const int wid  = threadIdx.x >> 6;
    const int lane = threadIdx.x & 63;
    const int node = blockIdx.x * 4 + wid;
    if (node >= N_NODES) return;

    const int start = __builtin_amdgcn_readfirstlane(rowptr[node]);
    const int end   = __builtin_amdgcn_readfirstlane(rowptr[node + 1]);
    const int deg   = end - start;

    const float nrm = norm[node];
    const float hnv = h[(size_t)node * FEAT + lane] * nrm;   // own channel in f32

    float pre;
    if (deg > 0) {
        float s1a = 0.f, s1b = 0.f, s1c = 0.f, s1d = 0.f;
        float s2a = 0.f, s2b = 0.f, s2c = 0.f, s2d = 0.f;
        float mx = -FLT_MAX, mn = FLT_MAX;
        int e = start;
        for (; e + 8 <= end; e += 8) {
            const int i0 = src[e + 0]; const int i1 = src[e + 1];
            const int i2 = src[e + 2]; const int i3 = src[e + 3];
            const int i4 = src[e + 4]; const int i5 = src[e + 5];
            const int i6 = src[e + 6]; const int i7 = src[e + 7];
            const float v0 = __half2float(hn[(size_t)i0 * FEAT + lane]);
            const float v1 = __half2float(hn[(size_t)i1 * FEAT + lane]);
            const float v2 = __half2float(hn[(size_t)i2 * FEAT + lane]);
            const float v3 = __half2float(hn[(size_t)i3 * FEAT + lane]);
            const float v4 = __half2float(hn[(size_t)i4 * FEAT + lane]);
            const float v5 = __half2float(hn[(size_t)i5 * FEAT + lane]);
            const float v6 = __half2float(hn[(size_t)i6 * FEAT + lane]);
            const float v7 = __half2float(hn[(size_t)i7 * FEAT + lane]);
            s1a += v0; s2a += v0 * v0; mx = fmaxf(mx, v0); mn = fminf(mn, v0);
            s1b += v1; s2b += v1 * v1; mx = fmaxf(mx, v1); mn = fminf(mn, v1);
            s1c += v2; s2c += v2 * v2; mx = fmaxf(mx, v2); mn = fminf(mn, v2);
            s1d += v3; s2d += v3 * v3; mx = fmaxf(mx, v3); mn = fminf(mn, v3);
            s1a += v4; s2a += v4 * v4; mx = fmaxf(mx, v4); mn = fminf(mn, v4);
            s1b += v5; s2b += v5 * v5; mx = fmaxf(mx, v5); mn = fminf(mn, v5);
            s1c += v6; s2c += v6 * v6; mx = fmaxf(mx, v6); mn = fminf(mn, v6);
            s1d += v7; s2d += v7 * v7; mx = fmaxf(mx, v7); mn = fminf(mn, v7);
        }
        if (e + 4 <= end) {
            const int i0 = src[e + 0]; const int i1 = src[e + 1];
            const int i2 = src[e + 2]; const int i3 = src[e + 3];
            const float v0 = __half2float(hn[(size_t)i0 * FEAT + lane]);
            const float v1 = __half2float(hn[(size_t)i1 * FEAT + lane]);
            const float v2 = __half2float(hn[(size_t)i2 * FEAT + lane]);
            const float v3 = __half2float(hn[(size_t)i3 * FEAT + lane]);
            s1a += v0; s2a += v0 * v0; mx = fmaxf(mx, v0); mn = fminf(mn, v0);
            s1b += v1; s2b += v1 * v1; mx = fmaxf(mx, v1); mn = fminf(mn, v1);
            s1c += v2; s2c += v2 * v2; mx = fmaxf(mx, v2); mn = fminf(mn, v2);
            s1d += v3; s2d += v3 * v3; mx = fmaxf(mx, v3); mn = fminf(mn, v3);
            e += 4;
        }
        for (; e < end; ++e) {
            const int s = src[e];
            const float v = __half2float(hn[(size_t)s * FEAT + lane]);
            s1a += v; s2a += v * v; mx = fmaxf(mx, v); mn = fminf(mn, v);
        }
        const float s1 = (s1a + s1b) + (s1c + s1d);
        const float s2 = (s2a + s2b) + (s2c + s2d);

        const float invd = 1.0f / (float)deg;
        const float mean = s1 * invd;
        const float var  = fmaxf(s2 * invd - mean * mean, 0.0f);   // relu(...)
        const float stdv = sqrtf(var + EPS_STD);
        const float logD = logf((float)deg + 1.0f);
        const float factor = nrm * (1.0f + logD * (1.0f / AVG_D_LOG) + AVG_D_LOG / logD)
                                 * (1.0f / 13.0f);
        pre = hnv * (1.0f / 13.0f) + (mean + mx + mn + stdv) * factor;
    } else {
        pre = hnv * (1.0f / 13.0f);              // zero-degree: only hn channel
    }
    out1[(size_t)node * FEAT + lane] = fmaxf(pre, 0.0f);     // ReLU
}

// Fallback (ws too small): fused f32 version, needs only rowptr in ws.
__global__ void build_rowptr(const int* __restrict__ dst, int* __restrict__ rowptr) {
    int n = blockIdx.x * blockDim.x + threadIdx.x;
    if (n > N_NODES) return;
    int lo = 0, hi = N_EDGES;
    while (lo < hi) {
        int mid = (lo + hi) >> 1;
        if (dst[mid] < n) lo = mid + 1; else hi = mid;
    }
    rowptr[n] = lo;
}

__global__ void __launch_bounds__(256) pna_agg_slow(
    const float* __restrict__ h, const float* __restrict__ norm,
    const int* __restrict__ src, const int* __restrict__ rowptr,
    float* __restrict__ out1)
{
    const int wid  = threadIdx.x >> 6;
    const int lane = threadIdx.x & 63;
    const int node = blockIdx.x * 4 + wid;
    if (node >= N_NODES) return;

    const int start = rowptr[node];
    const int end   = rowptr[node + 1];
    const int deg   = end - start;

    const float nrm = norm[node];
    const float hnv = h[(size_t)node * FEAT + lane] * nrm;

    float pre;
    if (deg > 0) {
        float s1 = 0.f, s2 = 0.f, mx = -FLT_MAX, mn = FLT_MAX;
        for (int e = start; e < end; ++e) {
            int s = src[e];
            float v = h[(size_t)s * FEAT + lane] * norm[s];
            s1 += v; s2 += v * v; mx = fmaxf(mx, v); mn = fminf(mn, v);
        }
        float invd = 1.0f / (float)deg;
        float mean = s1 * invd;
        float var  = fmaxf(s2 * invd - mean * mean, 0.0f);
        float stdv = sqrtf(var + EPS_STD);
        float logD = logf((float)deg + 1.0f);
        float factor = nrm * (1.0f + logD * (1.0f / AVG_D_LOG) + AVG_D_LOG / logD)
                           * (1.0f / 13.0f);
        pre = hnv * (1.0f / 13.0f) + (mean + mx + mn + stdv) * factor;
    } else {
        pre = hnv * (1.0f / 13.0f);
    }
    out1[(size_t)node * FEAT + lane] = fmaxf(pre, 0.0f);
}

// -------------------------------------------------- BN stats (2-stage) ------
__global__ void __launch_bounds__(256) bn_partial(
    const float* __restrict__ out1,
    double* __restrict__ psum, double* __restrict__ psumsq)
{
    const int tid = threadIdx.x;
    const int fb  = tid & 15;                    // feature block of 4
    const int grp = tid >> 4;                    // 0..15 node groups
    double s0 = 0, s1 = 0, s2 = 0, s3 = 0;
    double q0 = 0, q1 = 0, q2 = 0, q3 = 0;
    for (int n = blockIdx.x * 16 + grp; n < N_NODES; n += RED_BLOCKS * 16) {
        float4 v = *reinterpret_cast<const float4*>(out1 + (size_t)n * FEAT + fb * 4);
        s0 += (double)v.x; q0 += (double)v.x * (double)v.x;
        s1 += (double)v.y; q1 += (double)v.y * (double)v.y;
        s2 += (double)v.z; q2 += (double)v.z * (double)v.z;
        s3 += (double)v.w; q3 += (double)v.w * (double)v.w;
    }
    __shared__ double ls[256 * 4];
    __shared__ double lq[256 * 4];
    ls[tid * 4 + 0] = s0; ls[tid * 4 + 1] = s1; ls[tid * 4 + 2] = s2; ls[tid * 4 + 3] = s3;
    lq[tid * 4 + 0] = q0; lq[tid * 4 + 1] = q1; lq[tid * 4 + 2] = q2; lq[tid * 4 + 3] = q3;
    __syncthreads();
    if (tid < 64) {
        const int f = tid, fblk = f >> 2, j = f & 3;
        double S = 0, Q = 0;
        for (int g = 0; g < 16; ++g) {
            S += ls[(g * 16 + fblk) * 4 + j];
            Q += lq[(g * 16 + fblk) * 4 + j];
        }
        psum  [blockIdx.x * 64 + f] = S;
        psumsq[blockIdx.x * 64 + f] = Q;
    }
}

__global__ void bn_finalize(const double* __restrict__ psum,
                            const double* __restrict__ psumsq,
                            const float* __restrict__ w, const float* __restrict__ b,
                            float* __restrict__ scale, float* __restrict__ shift)
{
    int f = threadIdx.x;                         // 64 threads
    double s = 0.0, s2 = 0.0;
    for (int blk = 0; blk < RED_BLOCKS; ++blk) {
        s  += psum  [blk * 64 + f];
        s2 += psumsq[blk * 64 + f];
    }
    double mu   = s / (double)N_NODES;
    double var  = s2 / (double)N_NODES - mu * mu;   // biased (training-mode) var
    double rstd = 1.0 / sqrt(var + EPS_BN);
    float sc = (float)rstd * w[f];
    scale[f] = sc;
    shift[f] = b[f] - (float)mu * sc;
}

// ------------------------------------------------------- BN apply -----------
__global__ void __launch_bounds__(256) bn_apply(
    float* __restrict__ out,
    const float* __restrict__ scale, const float* __restrict__ shift)
{
    const size_t i4 = ((size_t)blockIdx.x * blockDim.x + threadIdx.x) * 4;
    if (i4 >= (size_t)N_NODES * FEAT) return;
    float4 v = *reinterpret_cast<const float4*>(out + i4);
    const int f = (int)(i4 & 63);
    v.x = v.x * scale[f + 0] + shift[f + 0];
    v.y = v.y * scale[f + 1] + shift[f + 1];
    v.z = v.z * scale[f + 2] + shift[f + 2];
    v.w = v.w * scale[f + 3] + shift[f + 3];
    *reinterpret_cast<float4*>(out + i4) = v;
}

// ---------------------------------------------------------------------------
extern "C" void kernel_launch(void* const* d_in, const int* in_sizes, int n_in,
                              void* d_out, int out_size, void* d_ws, size_t ws_size,
                              hipStream_t stream) {
    const float* h    = (const float*)d_in[0];
    const float* norm = (const float*)d_in[1];
    /* d_in[2] = e, unused */
    const float* bnw  = (const float*)d_in[3];
    const float* bnb  = (const float*)d_in[4];
    const int*   src  = (const int*)d_in[5];
    const int*   dst  = (const int*)d_in[6];
    float* out = (float*)d_out;

    const size_t hn_bytes = (size_t)N_NODES * FEAT * sizeof(__half);  // 12.8 MB
    char* ws = (char*)d_ws;

    // full layout: [hn_h][rowptr][psum][psumsq][scale][shift]
    size_t o = (hn_bytes + 255) & ~(size_t)255;
    __half* hnbuf = (__half*)ws;
    int* rowptr_f = (int*)(ws + o);   o += ((size_t)(N_NODES + 1) * sizeof(int) + 255) & ~(size_t)255;
    double* psum_f   = (double*)(ws + o); o += (size_t)RED_BLOCKS * 64 * sizeof(double);
    double* psumsq_f = (double*)(ws + o); o += (size_t)RED_BLOCKS * 64 * sizeof(double);
    float* scale_f   = (float*)(ws + o);  o += 256;
    float* shift_f   = (float*)(ws + o);  o += 256;
    const size_t need_full = o;

    // small layout (fallback): [rowptr][psum][psumsq][scale][shift]
    size_t so = 0;
    int* rowptr_s = (int*)(ws + so);
    so = ((size_t)(N_NODES + 1) * sizeof(int) + 255) & ~(size_t)255;
    double* psum_s   = (double*)(ws + so); so += (size_t)RED_BLOCKS * 64 * sizeof(double);
    double* psumsq_s = (double*)(ws + so); so += (size_t)RED_BLOCKS * 64 * sizeof(double);
    float* scale_s   = (float*)(ws + so);  so += 256;
    float* shift_s   = (float*)(ws + so);

    const bool fast = (ws_size >= need_full);
    int* rowptr     = fast ? rowptr_f : rowptr_s;
    double* psum    = fast ? psum_f   : psum_s;
    double* psumsq  = fast ? psumsq_f : psumsq_s;
    float* scale    = fast ? scale_f  : scale_s;
    float* shift    = fast ? shift_f  : shift_s;

    if (fast) {
        hn_rowptr<<<HN_BLOCKS + RP_BLOCKS, 256, 0, stream>>>(h, norm, dst, hnbuf, rowptr);
        pna_agg_fast<<<(N_NODES + 3) / 4, 256, 0, stream>>>(hnbuf, h, norm, src, rowptr, out);
    } else {
        build_rowptr<<<(N_NODES + 1 + 255) / 256, 256, 0, stream>>>(dst, rowptr);
        pna_agg_slow<<<(N_NODES + 3) / 4, 256, 0, stream>>>(h, norm, src, rowptr, out);
    }
    bn_partial<<<RED_BLOCKS, 256, 0, stream>>>(out, psum, psumsq);
    bn_finalize<<<1, 64, 0, stream>>>(psum, psumsq, bnw, bnb, scale, shift);
    bn_apply<<<((N_NODES * FEAT / 4) + 255) / 256, 256, 0, stream>>>(out, scale, shift);
}